// Round 9
// baseline (496.713 us; speedup 1.0000x reference)
//
#include <hip/hip_runtime.h>

// VQ quantizer forward: direct-from-L2 bf16-MFMA distance GEMM.
// B-fragments live in LDS in MFMA-fragment order (conflict-free ds_read_b128
// per chunk) instead of 64 registers -> 5 waves/SIMD (was 4). Single-buffered
// A-frag + w2 prefetch from L2. R7 float tail (proven). Fragment-ordered w
// staging, thresholds re-synced via LDS every 8 chunks, exact fp32 candidate
// refinement. x (16,256,64,64) fp32, w (2048,256) fp32.
// d_out = 16,777,216 floats (quantized, (b,c,h,w)) + 1 float (latent loss).

typedef __attribute__((ext_vector_type(8))) short short8;  // 8 bf16 (4 VGPR)
typedef __attribute__((ext_vector_type(4))) float f32x4;   // MFMA C/D

constexpr int NE   = 2048;
constexpr int DIM  = 256;
constexpr int HW   = 4096;
constexpr int NTOT = 16777216;
constexpr int ROWS   = 32;      // spatial rows per block
constexpr int CHUNK  = 64;      // codes per main-loop iteration
constexpr int NCHUNK = NE / CHUNK;
constexpr int CAP    = 64;      // candidate list capacity per row
constexpr float TAU   = 0.75f;  // collect window (bf16-MFMA err ~17 sigma)
constexpr float SLACK = 1.0f;   // ambiguity window triggering fp32 refine
constexpr float LOSS_SCALE = 0.25f / 16777216.0f;

__device__ __forceinline__ unsigned short f2bf(float f) {  // RNE fp32->bf16
    unsigned u = __builtin_bit_cast(unsigned, f);
    u += 0x7fffu + ((u >> 16) & 1u);
    return (unsigned short)(u >> 16);
}
// monotone float<->uint keys (works for negative distances too)
__device__ __forceinline__ unsigned fkey(float f) {
    unsigned u = __builtin_bit_cast(unsigned, f);
    return u ^ ((unsigned)((int)u >> 31) | 0x80000000u);
}
__device__ __forceinline__ float funkey(unsigned k) {
    unsigned u = (k & 0x80000000u) ? (k & 0x7fffffffu) : ~k;
    return __builtin_bit_cast(float, u);
}
// packed candidate/runmin entry: truncated fkey (21 bits kept) | code (11 bits)
__device__ __forceinline__ unsigned pack_dc(float d, int code) {
    return (fkey(d) & 0xFFFFF800u) | (unsigned)code;
}

// Kernel 1: -0.5*||w||^2 (pre-scaled for acc-init) + FRAGMENT-ORDERED bf16
// copy of w; also zero loss slot.
// wfrag layout: group g=code>>4 (16 codes); within group: [kk][quad][col][8e].
// vq_kernel loads aw[kk] at wfrag + g*4096 + kk*512 + lane*8 -- fully
// coalesced 1KB per instruction.
__global__ __launch_bounds__(256) void prep_kernel(const float* __restrict__ w,
                                                   unsigned short* __restrict__ wfrag,
                                                   float* __restrict__ w2,
                                                   float* __restrict__ loss_slot) {
    const int lane = threadIdx.x & 63;
    const int wv   = threadIdx.x >> 6;
    const int code = blockIdx.x * 4 + wv;   // one wave per code row
    float4 v = *reinterpret_cast<const float4*>(w + (size_t)code * DIM + lane * 4);
    float s = v.x * v.x + v.y * v.y + v.z * v.z + v.w * v.w;
#pragma unroll
    for (int off = 32; off > 0; off >>= 1) s += __shfl_down(s, off, 64);
    if (lane == 0) w2[code] = -0.5f * s;    // pre-scaled: acc-init consumes directly
    ushort4 u4;
    u4.x = f2bf(v.x); u4.y = f2bf(v.y); u4.z = f2bf(v.z); u4.w = f2bf(v.w);
    const size_t off = (size_t)(code >> 4) * 4096 + (lane >> 3) * 512 +
                       ((lane >> 1) & 3) * 128 + (code & 15) * 8 + (lane & 1) * 4;
    *reinterpret_cast<ushort4*>(wfrag + off) = u4;
    if (blockIdx.x == 0 && threadIdx.x == 0) *loss_slot = 0.0f;
}

__global__ __launch_bounds__(256, 5) void vq_kernel(const float* __restrict__ x,
                                                    const float* __restrict__ wg,
                                                    const unsigned short* __restrict__ wfrag,
                                                    const float* __restrict__ w2g,
                                                    float* __restrict__ out,
                                                    float* __restrict__ loss_slot) {
    // ubuf: main-loop xfrag (fragment-ordered bf16 x, 16 KB) / epilogue wst [16][260] f32
    __shared__ alignas(16) unsigned char ubuf[16896];
    __shared__ unsigned runmin[ROWS];     // packed (trunc fkey | code), atomicMin
    __shared__ unsigned cand[ROWS * CAP]; // packed entries (8 KB)
    __shared__ unsigned cnt[ROWS];
    __shared__ float    dbest[ROWS];
    __shared__ int      bestc[ROWS];
    __shared__ int      scnt[ROWS];
    __shared__ float    xn2[ROWS];        // per-row ||x||^2 (fp32 exact)

    const int tid = threadIdx.x;
    const int blk = blockIdx.x;
    const int b   = blk >> 7;             // 128 blocks per image (4096/32)
    const int hw0 = (blk & 127) << 5;
    const size_t base = (size_t)b * (DIM * HW) + hw0;

    const int wv   = tid >> 6;
    const int lane = tid & 63;
    const int col  = lane & 15;
    const int quad = lane >> 4;

    if (tid < ROWS) { runmin[tid] = 0xFFFFFFFFu; cnt[tid] = 0u; xn2[tid] = 0.f; }

    // ---- phase 1: stage x as bf16 in FRAGMENT ORDER [t][kk][quad][col][8e]
    // (t=row>>4, col=row&15; kk=dim>>5, quad=(dim>>3)&3, e=dim&7).
    // Per-chunk B-reads are then ds_read_b128 at lane*16 + imm -- conflict-free.
    unsigned short* xfrag = (unsigned short*)ubuf;   // 8192 shorts (16 KB)
    const int irow = tid & 31;
    const int cgrp = tid >> 5;            // 8 channel groups (e = cgrp)
    {
        float myxn2 = 0.f;
        const int tbase = (irow >> 4) * 4096 + (irow & 15) * 8 + cgrp;
        for (int it = 0; it < 32; ++it) {
            int c = it * 8 + cgrp;        // kk = it>>2, quad = it&3, e = cgrp
            float v = x[base + (size_t)c * HW + irow];
            xfrag[tbase + (it >> 2) * 512 + (it & 3) * 128] = f2bf(v);
            myxn2 = fmaf(v, v, myxn2);
        }
        atomicAdd(&xn2[irow], myxn2);
        __syncthreads();
    }
    const unsigned short* xl = xfrag + lane * 8;     // B-frag base (this lane)
#define BX(T, KK) (*reinterpret_cast<const short8*>(xl + (T) * 4096 + (KK) * 512))

    // ---- main loop: barrier-free chunk bodies, A-frags + w2 direct from
    // global (L2-hot), single-buffered prefetch issued right after last use;
    // B-frags from LDS per chunk. Lane-local running min + threshold,
    // re-synced via LDS runmin every 8 chunks. ----
    unsigned rm[2]  = {0xFFFFFFFFu, 0xFFFFFFFFu};
    float    thr[2] = {3.0e38f, 3.0e38f};
    short8 aw[8];
    // this wave's fragment base for chunk ch: wfrag + (ch*4+wv)*4096 + lane*8
    const unsigned short* wl = wfrag + (size_t)wv * 4096 + (size_t)lane * 8;
#pragma unroll
    for (int kk = 0; kk < 8; ++kk)        // chunk 0 A-frags
        aw[kk] = *reinterpret_cast<const short8*>(wl + kk * 512);
    float4 w2n = *reinterpret_cast<const float4*>(w2g + wv * 16 + quad * 4);

    // ---- chunk 0 (special): compute, row-sync threshold, then collect ----
    {
        const int cbase = wv * 16 + quad * 4;
        f32x4 acc[2];
#pragma unroll
        for (int nt = 0; nt < 2; ++nt)
            acc[nt] = (f32x4){w2n.x, w2n.y, w2n.z, w2n.w};
#pragma unroll
        for (int kk = 0; kk < 8; ++kk) {
            acc[0] = __builtin_amdgcn_mfma_f32_16x16x32_bf16(aw[kk], BX(0, kk), acc[0], 0, 0, 0);
            acc[1] = __builtin_amdgcn_mfma_f32_16x16x32_bf16(aw[kk], BX(1, kk), acc[1], 0, 0, 0);
        }
        // prefetch chunk 1 A-frags + w2 (after last use above)
        {
            const unsigned short* wnp = wl + 4 * 4096;
#pragma unroll
            for (int kk = 0; kk < 8; ++kk)
                aw[kk] = *reinterpret_cast<const short8*>(wnp + kk * 512);
            w2n = *reinterpret_cast<const float4*>(w2g + CHUNK + wv * 16 + quad * 4);
        }
        float dd0[2][4];
#pragma unroll
        for (int nt = 0; nt < 2; ++nt) {
            float ld = 3.0e38f; int lj = 0;
#pragma unroll
            for (int j = 0; j < 4; ++j) {
                dd0[nt][j] = -2.f * acc[nt][j];
                if (dd0[nt][j] < ld) { ld = dd0[nt][j]; lj = j; }
            }
            unsigned pk = pack_dc(ld, cbase + lj);
            unsigned po = (unsigned)__shfl_xor((int)pk, 16, 64);
            pk = po < pk ? po : pk;
            po = (unsigned)__shfl_xor((int)pk, 32, 64);
            pk = po < pk ? po : pk;
            if (quad == 0) atomicMin(&runmin[nt * 16 + col], pk);
        }
        __syncthreads();                       // runmin holds row min over chunk 0
#pragma unroll
        for (int nt = 0; nt < 2; ++nt) {
            rm[nt]  = runmin[nt * 16 + col];
            thr[nt] = funkey(rm[nt] & 0xFFFFF800u) + TAU;
            const int r = nt * 16 + col;
#pragma unroll
            for (int j = 0; j < 4; ++j) {
                if (dd0[nt][j] < thr[nt]) {
                    unsigned s_ = atomicAdd(&cnt[r], 1u);
                    if (s_ < (unsigned)CAP)
                        cand[r * CAP + s_] = pack_dc(dd0[nt][j], cbase + j);
                }
            }
        }
    }

    // ---- chunks 1..31; thr re-sync at ch = 9, 17, 25 ----
    for (int ch = 1; ch < NCHUNK; ++ch) {
        if ((ch & 7) == 1 && ch != 1) {
#pragma unroll
            for (int nt = 0; nt < 2; ++nt) {
                unsigned pk = rm[nt];
                unsigned po = (unsigned)__shfl_xor((int)pk, 16, 64);
                pk = po < pk ? po : pk;
                po = (unsigned)__shfl_xor((int)pk, 32, 64);
                pk = po < pk ? po : pk;
                if (quad == 0) atomicMin(&runmin[nt * 16 + col], pk);
            }
            __syncthreads();
#pragma unroll
            for (int nt = 0; nt < 2; ++nt) {
                unsigned rv = runmin[nt * 16 + col];
                if (rv < rm[nt]) rm[nt] = rv;
                thr[nt] = funkey(rm[nt] & 0xFFFFF800u) + TAU;
            }
        }
        const int cbase = ch * CHUNK + wv * 16 + quad * 4;
        f32x4 acc[2];
#pragma unroll
        for (int nt = 0; nt < 2; ++nt)
            acc[nt] = (f32x4){w2n.x, w2n.y, w2n.z, w2n.w};
#pragma unroll
        for (int kk = 0; kk < 8; ++kk) {
            acc[0] = __builtin_amdgcn_mfma_f32_16x16x32_bf16(aw[kk], BX(0, kk), acc[0], 0, 0, 0);
            acc[1] = __builtin_amdgcn_mfma_f32_16x16x32_bf16(aw[kk], BX(1, kk), acc[1], 0, 0, 0);
        }
        // prefetch next chunk A-frags + w2 (single buffer; WAR clears at issue)
        {
            const int cn = (ch + 1) & (NCHUNK - 1);
            const unsigned short* wnp = wl + (size_t)(cn * 4) * 4096;
#pragma unroll
            for (int kk = 0; kk < 8; ++kk)
                aw[kk] = *reinterpret_cast<const short8*>(wnp + kk * 512);
            w2n = *reinterpret_cast<const float4*>(w2g + cn * CHUNK + wv * 16 + quad * 4);
        }
        // tail: min/collect (covers the prefetch L2 latency)
#pragma unroll
        for (int nt = 0; nt < 2; ++nt) {
            const float d0 = -2.f * acc[nt][0];
            const float d1 = -2.f * acc[nt][1];
            const float d2 = -2.f * acc[nt][2];
            const float d3 = -2.f * acc[nt][3];
            float ld = d0; int lj = 0;
            if (d1 < ld) { ld = d1; lj = 1; }
            if (d2 < ld) { ld = d2; lj = 2; }
            if (d3 < ld) { ld = d3; lj = 3; }
            const unsigned pk = pack_dc(ld, cbase + lj);
            if (pk < rm[nt]) { rm[nt] = pk; thr[nt] = funkey(pk & 0xFFFFF800u) + TAU; }
            const int r = nt * 16 + col;
            if (d0 < thr[nt]) { unsigned s_ = atomicAdd(&cnt[r], 1u);
                if (s_ < (unsigned)CAP) cand[r * CAP + s_] = pack_dc(d0, cbase + 0); }
            if (d1 < thr[nt]) { unsigned s_ = atomicAdd(&cnt[r], 1u);
                if (s_ < (unsigned)CAP) cand[r * CAP + s_] = pack_dc(d1, cbase + 1); }
            if (d2 < thr[nt]) { unsigned s_ = atomicAdd(&cnt[r], 1u);
                if (s_ < (unsigned)CAP) cand[r * CAP + s_] = pack_dc(d2, cbase + 2); }
            if (d3 < thr[nt]) { unsigned s_ = atomicAdd(&cnt[r], 1u);
                if (s_ < (unsigned)CAP) cand[r * CAP + s_] = pack_dc(d3, cbase + 3); }
        }
    }
#undef BX

    // ---- deferred final reduction: cross-quad min once, one atomicMin ----
#pragma unroll
    for (int nt = 0; nt < 2; ++nt) {
        unsigned pk = rm[nt];
        unsigned po = (unsigned)__shfl_xor((int)pk, 16, 64);
        pk = po < pk ? po : pk;
        po = (unsigned)__shfl_xor((int)pk, 32, 64);
        pk = po < pk ? po : pk;
        if (quad == 0) atomicMin(&runmin[nt * 16 + col], pk);
    }
    __syncthreads();

    // ---- select: unambiguous rows decided by bf16; near-ties -> refine ----
    if (tid < ROWS) {
        const unsigned key = runmin[tid];
        const int   c1 = (int)(key & 0x7FFu);
        const float d1 = funkey(key & 0xFFFFF800u);
        const unsigned thv = ((fkey(d1 + SLACK)) & 0xFFFFF800u) | 0x7FFu;
        const int n = (int)min(cnt[tid], (unsigned)CAP);
        int m = 0; bool have_c1 = false;
        for (int t = 0; t < n; ++t) {
            unsigned e = cand[tid * CAP + t];
            if (e <= thv) {
                int code = (int)(e & 0x7FFu);
                if (code == c1) have_c1 = true;
                cand[tid * CAP + m++] = (unsigned)code;
            }
        }
        if (!have_c1 && m < CAP) cand[tid * CAP + m++] = (unsigned)c1;
        bestc[tid] = c1; dbest[tid] = d1;
        scnt[tid] = (m >= 2) ? m : 0;
    }
    __syncthreads();

    // ---- exact fp32 refinement (round-2 numerics), ~6% of rows ----
    // (w2g holds -0.5*||w||^2, so d = -2*(w2g[code] + x.w))
    for (int r = wv; r < ROWS; r += 4) {
        const int m = scnt[r];
        if (m == 0) continue;
        const size_t xb = base + r;
        float xr0 = x[xb + (size_t)(4 * lane + 0) * HW];
        float xr1 = x[xb + (size_t)(4 * lane + 1) * HW];
        float xr2 = x[xb + (size_t)(4 * lane + 2) * HW];
        float xr3 = x[xb + (size_t)(4 * lane + 3) * HW];
        float bd = 1e38f; int bc = 0;
        for (int t = 0; t < m; ++t) {
            const int code = (int)cand[r * CAP + t];
            float4 wv4 = *reinterpret_cast<const float4*>(wg + (size_t)code * DIM + lane * 4);
            float sum = xr0 * wv4.x + xr1 * wv4.y + xr2 * wv4.z + xr3 * wv4.w;
#pragma unroll
            for (int o = 1; o < 64; o <<= 1) sum += __shfl_xor(sum, o, 64);
            float d = -2.0f * (w2g[code] + sum);
            if (t == 0 || d < bd || (d == bd && code < bc)) { bd = d; bc = code; }
        }
        if (lane == 0) { bestc[r] = bc; dbest[r] = bd; }
    }
    __syncthreads();

    // ---- loss via identity: sum_r (d_best + ||x||^2) = sum (q-x)^2 ----
    if (tid == 0) {
        float ls = 0.f;
        for (int r = 0; r < ROWS; ++r) ls += dbest[r] + xn2[r];
        atomicAdd(loss_slot, ls * LOSS_SCALE);
    }

    // ---- epilogue: 2 passes x 16 rows; stage codewords fp32 -> float4 out ----
    float* wst = (float*)ubuf;                    // [16][260]
    const int rl = tid >> 4;
    const int tt = tid & 15;
    const int ec = tid >> 2;                      // 0..63 (channel group)
    const int ei = (tid & 3) * 4;                 // 0,4,8,12 (spatial i0)
    for (int h = 0; h < 2; ++h) {
        __syncthreads();
        const float* wrow = wg + (size_t)bestc[h * 16 + rl] * DIM;
#pragma unroll
        for (int it = 0; it < 4; ++it) {
            const int c4 = it * 16 + tt;
            *reinterpret_cast<float4*>(wst + rl * 260 + c4 * 4) =
                *reinterpret_cast<const float4*>(wrow + c4 * 4);
        }
        __syncthreads();
#pragma unroll
        for (int it = 0; it < 4; ++it) {
            const int c = it * 64 + ec;
            float4 o;
            o.x = wst[(ei + 0) * 260 + c];
            o.y = wst[(ei + 1) * 260 + c];
            o.z = wst[(ei + 2) * 260 + c];
            o.w = wst[(ei + 3) * 260 + c];
            *reinterpret_cast<float4*>(out + base + (size_t)c * HW + h * 16 + ei) = o;
        }
    }
}

extern "C" void kernel_launch(void* const* d_in, const int* in_sizes, int n_in,
                              void* d_out, int out_size, void* d_ws, size_t ws_size,
                              hipStream_t stream) {
    const float* x = (const float*)d_in[0];
    const float* w = (const float*)d_in[1];
    float* out       = (float*)d_out;
    float* loss_slot = out + NTOT;
    unsigned short* wfrag = (unsigned short*)d_ws;   // 1 MB fragment-ordered bf16 w
    float* w2 = (float*)((char*)d_ws + (size_t)NE * DIM * sizeof(unsigned short));

    prep_kernel<<<NE / 4, 256, 0, stream>>>(w, wfrag, w2, loss_slot);
    vq_kernel<<<65536 / ROWS, 256, 0, stream>>>(x, w, wfrag, w2, out, loss_slot);
}

// Round 10
// 233.298 us; speedup vs baseline: 2.1291x; 2.1291x over previous
//
#include <hip/hip_runtime.h>

// VQ quantizer forward: direct-from-L2 bf16-MFMA distance GEMM.
// R7 structure (ROWS=32 / nt=2 / 4-wave class, proven 135us) with two
// zero-register latency fixes: (1) acc zero-init + w2 consumed in TAIL
// (removes chunk-head ds_read->MFMA chain); (2) aw prefetch interleaved
// per-kk into the MFMA loop (earliest issue, ~300cy more L2 cover).
// Fragment-ordered w staging, lane-local thresholds re-synced every 8
// chunks, exact fp32 candidate refinement. x (16,256,64,64) fp32,
// w (2048,256) fp32. d_out = 16,777,216 floats + 1 float (latent loss).

typedef __attribute__((ext_vector_type(8))) short short8;  // 8 bf16 (4 VGPR)
typedef __attribute__((ext_vector_type(4))) float f32x4;   // MFMA C/D

constexpr int NE   = 2048;
constexpr int DIM  = 256;
constexpr int HW   = 4096;
constexpr int NTOT = 16777216;
constexpr int ROWS   = 32;      // spatial rows per block
constexpr int CHUNK  = 64;      // codes per main-loop iteration
constexpr int NCHUNK = NE / CHUNK;
constexpr int CAP    = 64;      // candidate list capacity per row
constexpr float TAU   = 0.75f;  // collect window (bf16-MFMA err ~17 sigma)
constexpr float SLACK = 1.0f;   // ambiguity window triggering fp32 refine
constexpr float LOSS_SCALE = 0.25f / 16777216.0f;

__device__ __forceinline__ unsigned short f2bf(float f) {  // RNE fp32->bf16
    unsigned u = __builtin_bit_cast(unsigned, f);
    u += 0x7fffu + ((u >> 16) & 1u);
    return (unsigned short)(u >> 16);
}
// monotone float<->uint keys (works for negative distances too)
__device__ __forceinline__ unsigned fkey(float f) {
    unsigned u = __builtin_bit_cast(unsigned, f);
    return u ^ ((unsigned)((int)u >> 31) | 0x80000000u);
}
__device__ __forceinline__ float funkey(unsigned k) {
    unsigned u = (k & 0x80000000u) ? (k & 0x7fffffffu) : ~k;
    return __builtin_bit_cast(float, u);
}
// packed candidate/runmin entry: truncated fkey (21 bits kept) | code (11 bits)
__device__ __forceinline__ unsigned pack_dc(float d, int code) {
    return (fkey(d) & 0xFFFFF800u) | (unsigned)code;
}

// Kernel 1: ||w||^2 + FRAGMENT-ORDERED bf16 copy of w; also zero loss slot.
// wfrag layout: group g=code>>4 (16 codes); within group: [kk][quad][col][8e].
// vq_kernel loads aw[kk] at wfrag + g*4096 + kk*512 + lane*8 -- fully
// coalesced 1KB per instruction.
__global__ __launch_bounds__(256) void prep_kernel(const float* __restrict__ w,
                                                   unsigned short* __restrict__ wfrag,
                                                   float* __restrict__ w2,
                                                   float* __restrict__ loss_slot) {
    const int lane = threadIdx.x & 63;
    const int wv   = threadIdx.x >> 6;
    const int code = blockIdx.x * 4 + wv;   // one wave per code row
    float4 v = *reinterpret_cast<const float4*>(w + (size_t)code * DIM + lane * 4);
    float s = v.x * v.x + v.y * v.y + v.z * v.z + v.w * v.w;
#pragma unroll
    for (int off = 32; off > 0; off >>= 1) s += __shfl_down(s, off, 64);
    if (lane == 0) w2[code] = s;            // +||w||^2 (consumed in tail fmaf)
    ushort4 u4;
    u4.x = f2bf(v.x); u4.y = f2bf(v.y); u4.z = f2bf(v.z); u4.w = f2bf(v.w);
    const size_t off = (size_t)(code >> 4) * 4096 + (lane >> 3) * 512 +
                       ((lane >> 1) & 3) * 128 + (code & 15) * 8 + (lane & 1) * 4;
    *reinterpret_cast<ushort4*>(wfrag + off) = u4;
    if (blockIdx.x == 0 && threadIdx.x == 0) *loss_slot = 0.0f;
}

__global__ __launch_bounds__(256, 4) void vq_kernel(const float* __restrict__ x,
                                                    const float* __restrict__ wg,
                                                    const unsigned short* __restrict__ wfrag,
                                                    const float* __restrict__ w2g,
                                                    float* __restrict__ out,
                                                    float* __restrict__ loss_slot) {
    // ubuf reused: phase1 bf16 x-transpose [32][264] / epilogue staging [16][260] f32
    __shared__ alignas(16) unsigned char ubuf[16896];
    __shared__ unsigned runmin[ROWS];     // packed (trunc fkey | code), atomicMin
    __shared__ unsigned cand[ROWS * CAP]; // packed entries (8 KB)
    __shared__ unsigned cnt[ROWS];
    __shared__ float    dbest[ROWS];
    __shared__ int      bestc[ROWS];
    __shared__ int      scnt[ROWS];
    __shared__ float    xn2[ROWS];        // per-row ||x||^2 (fp32 exact)
    __shared__ float    w2l[NE];          // ||w||^2 staged once (8 KB)

    const int tid = threadIdx.x;
    const int blk = blockIdx.x;
    const int b   = blk >> 7;             // 128 blocks per image (4096/32)
    const int hw0 = (blk & 127) << 5;
    const size_t base = (size_t)b * (DIM * HW) + hw0;

    const int wv   = tid >> 6;
    const int lane = tid & 63;
    const int col  = lane & 15;
    const int quad = lane >> 4;

    if (tid < ROWS) { runmin[tid] = 0xFFFFFFFFu; cnt[tid] = 0u; xn2[tid] = 0.f; }

    // stage w2 -> LDS (visibility covered by phase-1 barriers)
    {
        float4* dst = reinterpret_cast<float4*>(w2l);
        const float4* src = reinterpret_cast<const float4*>(w2g);
        dst[tid]       = src[tid];
        dst[tid + 256] = src[tid + 256];
    }

    // ---- phase 1: stage x as bf16 (one pass, 32 rows), B-frags = ds_read ----
    unsigned short* xst = (unsigned short*)ubuf;  // [32][264] bf16
    short8 bx[2][8];                      // B[k=kk*32+quad*8+j][n=nt*16+col]
    const int irow = tid & 31;
    const int cgrp = tid >> 5;
    {
        float myxn2 = 0.f;
        for (int it = 0; it < 32; ++it) {
            int c = it * 8 + cgrp;
            float v = x[base + (size_t)c * HW + irow];
            xst[irow * 264 + c] = f2bf(v);
            myxn2 = fmaf(v, v, myxn2);
        }
        atomicAdd(&xn2[irow], myxn2);
        __syncthreads();
#pragma unroll
        for (int t = 0; t < 2; ++t) {
            const unsigned short* xr = xst + (t * 16 + col) * 264 + quad * 8;
#pragma unroll
            for (int kk = 0; kk < 8; ++kk)
                bx[t][kk] = *reinterpret_cast<const short8*>(xr + kk * 32);
        }
    }

    // ---- main loop: barrier-free chunk bodies, A-frags direct from global
    // (L2-hot wfrag, coalesced 1KB loads). aw prefetch interleaved per-kk
    // (issued right after each aw[kk]'s last MFMA use). acc zero-init; w2
    // ds_read issued at head, consumed only in the tail fmaf. Lane-local
    // running min + threshold, re-synced via LDS runmin every 8 chunks. ----
    unsigned rm[2]  = {0xFFFFFFFFu, 0xFFFFFFFFu};
    float    thr[2] = {3.0e38f, 3.0e38f};
    short8 aw[8];
    // this wave's fragment base for chunk ch: wfrag + (ch*4+wv)*4096 + lane*8
    const unsigned short* wl = wfrag + (size_t)wv * 4096 + (size_t)lane * 8;
#pragma unroll
    for (int kk = 0; kk < 8; ++kk)        // chunk 0 A-frags
        aw[kk] = *reinterpret_cast<const short8*>(wl + kk * 512);

    // ---- chunk 0 (special): compute, row-sync threshold, then collect ----
    {
        const int cbase = wv * 16 + quad * 4;
        const float4 w2v = *reinterpret_cast<const float4*>(&w2l[cbase]);
        const unsigned short* wnp = wl + 4 * 4096;    // chunk 1
        f32x4 acc[2];
#pragma unroll
        for (int nt = 0; nt < 2; ++nt)
            acc[nt] = (f32x4){0.f, 0.f, 0.f, 0.f};
#pragma unroll
        for (int kk = 0; kk < 8; ++kk) {
            acc[0] = __builtin_amdgcn_mfma_f32_16x16x32_bf16(aw[kk], bx[0][kk], acc[0], 0, 0, 0);
            acc[1] = __builtin_amdgcn_mfma_f32_16x16x32_bf16(aw[kk], bx[1][kk], acc[1], 0, 0, 0);
            aw[kk] = *reinterpret_cast<const short8*>(wnp + kk * 512);  // prefetch ch1
        }
        float dd0[2][4];
#pragma unroll
        for (int nt = 0; nt < 2; ++nt) {
            const float w2a[4] = {w2v.x, w2v.y, w2v.z, w2v.w};
            float ld = 3.0e38f; int lj = 0;
#pragma unroll
            for (int j = 0; j < 4; ++j) {
                dd0[nt][j] = fmaf(-2.f, acc[nt][j], w2a[j]);
                if (dd0[nt][j] < ld) { ld = dd0[nt][j]; lj = j; }
            }
            unsigned pk = pack_dc(ld, cbase + lj);
            unsigned po = (unsigned)__shfl_xor((int)pk, 16, 64);
            pk = po < pk ? po : pk;
            po = (unsigned)__shfl_xor((int)pk, 32, 64);
            pk = po < pk ? po : pk;
            if (quad == 0) atomicMin(&runmin[nt * 16 + col], pk);
        }
        __syncthreads();                       // runmin holds row min over chunk 0
#pragma unroll
        for (int nt = 0; nt < 2; ++nt) {
            rm[nt]  = runmin[nt * 16 + col];
            thr[nt] = funkey(rm[nt] & 0xFFFFF800u) + TAU;
            const int r = nt * 16 + col;
#pragma unroll
            for (int j = 0; j < 4; ++j) {
                if (dd0[nt][j] < thr[nt]) {
                    unsigned s_ = atomicAdd(&cnt[r], 1u);
                    if (s_ < (unsigned)CAP)
                        cand[r * CAP + s_] = pack_dc(dd0[nt][j], cbase + j);
                }
            }
        }
    }

    // ---- chunks 1..31; thr re-sync at ch = 9, 17, 25 ----
    for (int ch = 1; ch < NCHUNK; ++ch) {
        if ((ch & 7) == 1 && ch != 1) {
#pragma unroll
            for (int nt = 0; nt < 2; ++nt) {
                unsigned pk = rm[nt];
                unsigned po = (unsigned)__shfl_xor((int)pk, 16, 64);
                pk = po < pk ? po : pk;
                po = (unsigned)__shfl_xor((int)pk, 32, 64);
                pk = po < pk ? po : pk;
                if (quad == 0) atomicMin(&runmin[nt * 16 + col], pk);
            }
            __syncthreads();
#pragma unroll
            for (int nt = 0; nt < 2; ++nt) {
                unsigned rv = runmin[nt * 16 + col];
                if (rv < rm[nt]) rm[nt] = rv;
                thr[nt] = funkey(rm[nt] & 0xFFFFF800u) + TAU;
            }
        }
        const int cbase = ch * CHUNK + wv * 16 + quad * 4;
        // w2 ds_read issued here, consumed only in the tail (16 MFMAs of cover)
        const float4 w2v = *reinterpret_cast<const float4*>(&w2l[cbase]);
        const unsigned short* wnp =
            wl + (size_t)(((ch + 1) & (NCHUNK - 1)) * 4) * 4096;
        f32x4 acc[2];
#pragma unroll
        for (int nt = 0; nt < 2; ++nt)
            acc[nt] = (f32x4){0.f, 0.f, 0.f, 0.f};
#pragma unroll
        for (int kk = 0; kk < 8; ++kk) {
            acc[0] = __builtin_amdgcn_mfma_f32_16x16x32_bf16(aw[kk], bx[0][kk], acc[0], 0, 0, 0);
            acc[1] = __builtin_amdgcn_mfma_f32_16x16x32_bf16(aw[kk], bx[1][kk], acc[1], 0, 0, 0);
            // prefetch next chunk's aw[kk] right after its last use (WAR in order)
            aw[kk] = *reinterpret_cast<const short8*>(wnp + kk * 512);
        }
        // tail: d = fmaf(-2, acc, w2); min/collect (covers prefetch L2 latency)
#pragma unroll
        for (int nt = 0; nt < 2; ++nt) {
            const float w2a[4] = {w2v.x, w2v.y, w2v.z, w2v.w};
            const float d0 = fmaf(-2.f, acc[nt][0], w2a[0]);
            const float d1 = fmaf(-2.f, acc[nt][1], w2a[1]);
            const float d2 = fmaf(-2.f, acc[nt][2], w2a[2]);
            const float d3 = fmaf(-2.f, acc[nt][3], w2a[3]);
            float ld = d0; int lj = 0;
            if (d1 < ld) { ld = d1; lj = 1; }
            if (d2 < ld) { ld = d2; lj = 2; }
            if (d3 < ld) { ld = d3; lj = 3; }
            const unsigned pk = pack_dc(ld, cbase + lj);
            if (pk < rm[nt]) { rm[nt] = pk; thr[nt] = funkey(pk & 0xFFFFF800u) + TAU; }
            const int r = nt * 16 + col;
            if (d0 < thr[nt]) { unsigned s_ = atomicAdd(&cnt[r], 1u);
                if (s_ < (unsigned)CAP) cand[r * CAP + s_] = pack_dc(d0, cbase + 0); }
            if (d1 < thr[nt]) { unsigned s_ = atomicAdd(&cnt[r], 1u);
                if (s_ < (unsigned)CAP) cand[r * CAP + s_] = pack_dc(d1, cbase + 1); }
            if (d2 < thr[nt]) { unsigned s_ = atomicAdd(&cnt[r], 1u);
                if (s_ < (unsigned)CAP) cand[r * CAP + s_] = pack_dc(d2, cbase + 2); }
            if (d3 < thr[nt]) { unsigned s_ = atomicAdd(&cnt[r], 1u);
                if (s_ < (unsigned)CAP) cand[r * CAP + s_] = pack_dc(d3, cbase + 3); }
        }
    }

    // ---- deferred final reduction: cross-quad min once, one atomicMin ----
#pragma unroll
    for (int nt = 0; nt < 2; ++nt) {
        unsigned pk = rm[nt];
        unsigned po = (unsigned)__shfl_xor((int)pk, 16, 64);
        pk = po < pk ? po : pk;
        po = (unsigned)__shfl_xor((int)pk, 32, 64);
        pk = po < pk ? po : pk;
        if (quad == 0) atomicMin(&runmin[nt * 16 + col], pk);
    }
    __syncthreads();

    // ---- select: unambiguous rows decided by bf16; near-ties -> refine ----
    if (tid < ROWS) {
        const unsigned key = runmin[tid];
        const int   c1 = (int)(key & 0x7FFu);
        const float d1 = funkey(key & 0xFFFFF800u);
        const unsigned thv = ((fkey(d1 + SLACK)) & 0xFFFFF800u) | 0x7FFu;
        const int n = (int)min(cnt[tid], (unsigned)CAP);
        int m = 0; bool have_c1 = false;
        for (int t = 0; t < n; ++t) {
            unsigned e = cand[tid * CAP + t];
            if (e <= thv) {
                int code = (int)(e & 0x7FFu);
                if (code == c1) have_c1 = true;
                cand[tid * CAP + m++] = (unsigned)code;
            }
        }
        if (!have_c1 && m < CAP) cand[tid * CAP + m++] = (unsigned)c1;
        bestc[tid] = c1; dbest[tid] = d1;
        scnt[tid] = (m >= 2) ? m : 0;
    }
    __syncthreads();

    // ---- exact fp32 refinement (round-2 numerics), ~6% of rows ----
    // (w2l holds +||w||^2, so d = fmaf(-2, sum, w2l[code]))
    for (int r = wv; r < ROWS; r += 4) {
        const int m = scnt[r];
        if (m == 0) continue;
        const size_t xb = base + r;
        float xr0 = x[xb + (size_t)(4 * lane + 0) * HW];
        float xr1 = x[xb + (size_t)(4 * lane + 1) * HW];
        float xr2 = x[xb + (size_t)(4 * lane + 2) * HW];
        float xr3 = x[xb + (size_t)(4 * lane + 3) * HW];
        float bd = 1e38f; int bc = 0;
        for (int t = 0; t < m; ++t) {
            const int code = (int)cand[r * CAP + t];
            float4 wv4 = *reinterpret_cast<const float4*>(wg + (size_t)code * DIM + lane * 4);
            float sum = xr0 * wv4.x + xr1 * wv4.y + xr2 * wv4.z + xr3 * wv4.w;
#pragma unroll
            for (int o = 1; o < 64; o <<= 1) sum += __shfl_xor(sum, o, 64);
            float d = fmaf(-2.0f, sum, w2l[code]);
            if (t == 0 || d < bd || (d == bd && code < bc)) { bd = d; bc = code; }
        }
        if (lane == 0) { bestc[r] = bc; dbest[r] = bd; }
    }
    __syncthreads();

    // ---- loss via identity: sum_r (d_best + ||x||^2) = sum (q-x)^2 ----
    if (tid == 0) {
        float ls = 0.f;
        for (int r = 0; r < ROWS; ++r) ls += dbest[r] + xn2[r];
        atomicAdd(loss_slot, ls * LOSS_SCALE);
    }

    // ---- epilogue: 2 passes x 16 rows; stage codewords fp32 -> float4 out ----
    float* wst = (float*)ubuf;                    // [16][260]
    const int rl = tid >> 4;
    const int tt = tid & 15;
    const int ec = tid >> 2;                      // 0..63 (channel group)
    const int ei = (tid & 3) * 4;                 // 0,4,8,12 (spatial i0)
    for (int h = 0; h < 2; ++h) {
        __syncthreads();
        const float* wrow = wg + (size_t)bestc[h * 16 + rl] * DIM;
#pragma unroll
        for (int it = 0; it < 4; ++it) {
            const int c4 = it * 16 + tt;
            *reinterpret_cast<float4*>(wst + rl * 260 + c4 * 4) =
                *reinterpret_cast<const float4*>(wrow + c4 * 4);
        }
        __syncthreads();
#pragma unroll
        for (int it = 0; it < 4; ++it) {
            const int c = it * 64 + ec;
            float4 o;
            o.x = wst[(ei + 0) * 260 + c];
            o.y = wst[(ei + 1) * 260 + c];
            o.z = wst[(ei + 2) * 260 + c];
            o.w = wst[(ei + 3) * 260 + c];
            *reinterpret_cast<float4*>(out + base + (size_t)c * HW + h * 16 + ei) = o;
        }
    }
}

extern "C" void kernel_launch(void* const* d_in, const int* in_sizes, int n_in,
                              void* d_out, int out_size, void* d_ws, size_t ws_size,
                              hipStream_t stream) {
    const float* x = (const float*)d_in[0];
    const float* w = (const float*)d_in[1];
    float* out       = (float*)d_out;
    float* loss_slot = out + NTOT;
    unsigned short* wfrag = (unsigned short*)d_ws;   // 1 MB fragment-ordered bf16 w
    float* w2 = (float*)((char*)d_ws + (size_t)NE * DIM * sizeof(unsigned short));

    prep_kernel<<<NE / 4, 256, 0, stream>>>(w, wfrag, w2, loss_slot);
    vq_kernel<<<65536 / ROWS, 256, 0, stream>>>(x, w, wfrag, w2, out, loss_slot);
}

// Round 12
// 215.010 us; speedup vs baseline: 2.3102x; 1.0851x over previous
//
#include <hip/hip_runtime.h>

// VQ quantizer forward: direct-from-L2 bf16-MFMA distance GEMM.
// ROWS=32 / nt=2 (2 MFMA chains for ILP) / single-buffered A-frags, register
// cap forced to 4 waves/SIMD via __launch_bounds__(256,4). Fragment-ordered w
// staging, lane-local running-min thresholds re-synced via LDS every 8 chunks,
// exact fp32 candidate refinement. x (16,256,64,64) fp32, w (2048,256) fp32.
// d_out = 16,777,216 floats (quantized, (b,c,h,w)) + 1 float (latent loss).
//
// NOTE (R8-R10 lessons): this kernel sits at EXACTLY 128 combined VGPR+AGPR
// (bx 64 AGPR + aw 32 + acc 8 + temps). Any added main-loop liveness (held
// w2v across MFMAs, packed-key temps across a branch, tighter bounds) spills
// to scratch and regresses 10-220%. Do not touch the main loop's liveness.

typedef __attribute__((ext_vector_type(8))) short short8;  // 8 bf16 (4 VGPR)
typedef __attribute__((ext_vector_type(4))) float f32x4;   // MFMA C/D

constexpr int NE   = 2048;
constexpr int DIM  = 256;
constexpr int HW   = 4096;
constexpr int NTOT = 16777216;
constexpr int ROWS   = 32;      // spatial rows per block
constexpr int CHUNK  = 64;      // codes per main-loop iteration
constexpr int NCHUNK = NE / CHUNK;
constexpr int CAP    = 64;      // candidate list capacity per row
constexpr float TAU   = 0.75f;  // collect window (bf16-MFMA err ~17 sigma)
constexpr float SLACK = 1.0f;   // ambiguity window triggering fp32 refine
constexpr float LOSS_SCALE = 0.25f / 16777216.0f;

__device__ __forceinline__ unsigned short f2bf(float f) {  // RNE fp32->bf16
    unsigned u = __builtin_bit_cast(unsigned, f);
    u += 0x7fffu + ((u >> 16) & 1u);
    return (unsigned short)(u >> 16);
}
// monotone float<->uint keys (works for negative distances too)
__device__ __forceinline__ unsigned fkey(float f) {
    unsigned u = __builtin_bit_cast(unsigned, f);
    return u ^ ((unsigned)((int)u >> 31) | 0x80000000u);
}
__device__ __forceinline__ float funkey(unsigned k) {
    unsigned u = (k & 0x80000000u) ? (k & 0x7fffffffu) : ~k;
    return __builtin_bit_cast(float, u);
}
// packed candidate/runmin entry: truncated fkey (21 bits kept) | code (11 bits)
__device__ __forceinline__ unsigned pack_dc(float d, int code) {
    return (fkey(d) & 0xFFFFF800u) | (unsigned)code;
}

// Kernel 1: -0.5*||w||^2 (pre-scaled for acc-init) + FRAGMENT-ORDERED bf16
// copy of w; also zero loss slot.
// wfrag layout: group g=code>>4 (16 codes); within group: [kk][quad][col][8e].
// vq_kernel loads aw[kk] at wfrag + g*4096 + kk*512 + lane*8 -- fully
// coalesced 1KB per instruction.
__global__ __launch_bounds__(256) void prep_kernel(const float* __restrict__ w,
                                                   unsigned short* __restrict__ wfrag,
                                                   float* __restrict__ w2,
                                                   float* __restrict__ loss_slot) {
    const int lane = threadIdx.x & 63;
    const int wv   = threadIdx.x >> 6;
    const int code = blockIdx.x * 4 + wv;   // one wave per code row
    float4 v = *reinterpret_cast<const float4*>(w + (size_t)code * DIM + lane * 4);
    float s = v.x * v.x + v.y * v.y + v.z * v.z + v.w * v.w;
#pragma unroll
    for (int off = 32; off > 0; off >>= 1) s += __shfl_down(s, off, 64);
    if (lane == 0) w2[code] = -0.5f * s;    // pre-scaled: acc-init consumes directly
    ushort4 u4;
    u4.x = f2bf(v.x); u4.y = f2bf(v.y); u4.z = f2bf(v.z); u4.w = f2bf(v.w);
    const size_t off = (size_t)(code >> 4) * 4096 + (lane >> 3) * 512 +
                       ((lane >> 1) & 3) * 128 + (code & 15) * 8 + (lane & 1) * 4;
    *reinterpret_cast<ushort4*>(wfrag + off) = u4;
    if (blockIdx.x == 0 && threadIdx.x == 0) *loss_slot = 0.0f;
}

__global__ __launch_bounds__(256, 4) void vq_kernel(const float* __restrict__ x,
                                                    const float* __restrict__ wg,
                                                    const unsigned short* __restrict__ wfrag,
                                                    const float* __restrict__ w2g,
                                                    float* __restrict__ out,
                                                    float* __restrict__ loss_slot) {
    // ubuf reused: phase1 bf16 x-transpose [32][264] / epilogue staging [16][260] f32
    __shared__ alignas(16) unsigned char ubuf[16896];
    __shared__ unsigned runmin[ROWS];     // packed (trunc fkey | code), atomicMin
    __shared__ unsigned cand[ROWS * CAP]; // packed entries (8 KB)
    __shared__ unsigned cnt[ROWS];
    __shared__ float    dbest[ROWS];
    __shared__ int      bestc[ROWS];
    __shared__ int      scnt[ROWS];
    __shared__ float    xn2[ROWS];        // per-row ||x||^2 (fp32 exact)
    __shared__ float    w2l[NE];          // -0.5*||w||^2 staged once (8 KB)

    const int tid = threadIdx.x;
    const int blk = blockIdx.x;
    const int b   = blk >> 7;             // 128 blocks per image (4096/32)
    const int hw0 = (blk & 127) << 5;
    const size_t base = (size_t)b * (DIM * HW) + hw0;

    const int wv   = tid >> 6;
    const int lane = tid & 63;
    const int col  = lane & 15;
    const int quad = lane >> 4;

    if (tid < ROWS) { runmin[tid] = 0xFFFFFFFFu; cnt[tid] = 0u; xn2[tid] = 0.f; }

    // stage w2 -> LDS (visibility covered by phase-1 barriers)
    {
        float4* dst = reinterpret_cast<float4*>(w2l);
        const float4* src = reinterpret_cast<const float4*>(w2g);
        dst[tid]       = src[tid];
        dst[tid + 256] = src[tid + 256];
    }

    // ---- phase 1: stage x as bf16 (one pass, 32 rows), B-frags = ds_read ----
    unsigned short* xst = (unsigned short*)ubuf;  // [32][264] bf16
    short8 bx[2][8];                      // B[k=kk*32+quad*8+j][n=nt*16+col]
    const int irow = tid & 31;
    const int cgrp = tid >> 5;
    {
        float myxn2 = 0.f;
        for (int it = 0; it < 32; ++it) {
            int c = it * 8 + cgrp;
            float v = x[base + (size_t)c * HW + irow];
            xst[irow * 264 + c] = f2bf(v);
            myxn2 = fmaf(v, v, myxn2);
        }
        atomicAdd(&xn2[irow], myxn2);
        __syncthreads();
#pragma unroll
        for (int t = 0; t < 2; ++t) {
            const unsigned short* xr = xst + (t * 16 + col) * 264 + quad * 8;
#pragma unroll
            for (int kk = 0; kk < 8; ++kk)
                bx[t][kk] = *reinterpret_cast<const short8*>(xr + kk * 32);
        }
    }

    // ---- main loop: barrier-free chunk bodies, A-frags direct from global
    // (L2-hot wfrag, coalesced 1KB loads), SINGLE-buffered: prefetch of ch+1
    // issues right after the last MFMA reads aw; the tail VALU covers the L2
    // latency. Lane-local running min + threshold, re-synced via LDS runmin
    // every 8 chunks. ----
    unsigned rm[2]  = {0xFFFFFFFFu, 0xFFFFFFFFu};
    float    thr[2] = {3.0e38f, 3.0e38f};
    short8 aw[8];
    // this wave's fragment base for chunk ch: wfrag + (ch*4+wv)*4096 + lane*8
    const unsigned short* wl = wfrag + (size_t)wv * 4096 + (size_t)lane * 8;
#pragma unroll
    for (int kk = 0; kk < 8; ++kk)        // chunk 0 A-frags
        aw[kk] = *reinterpret_cast<const short8*>(wl + kk * 512);

    // ---- chunk 0 (special): compute, row-sync threshold, then collect ----
    {
        const int cbase = wv * 16 + quad * 4;
        const float4 w2v = *reinterpret_cast<const float4*>(&w2l[cbase]);
        f32x4 acc[2];
#pragma unroll
        for (int nt = 0; nt < 2; ++nt)
            acc[nt] = (f32x4){w2v.x, w2v.y, w2v.z, w2v.w};
#pragma unroll
        for (int kk = 0; kk < 8; ++kk)
#pragma unroll
            for (int nt = 0; nt < 2; ++nt)
                acc[nt] = __builtin_amdgcn_mfma_f32_16x16x32_bf16(aw[kk], bx[nt][kk],
                                                                  acc[nt], 0, 0, 0);
        // prefetch chunk 1 into aw (after last use above)
        {
            const unsigned short* wnp = wl + 4 * 4096;
#pragma unroll
            for (int kk = 0; kk < 8; ++kk)
                aw[kk] = *reinterpret_cast<const short8*>(wnp + kk * 512);
        }
        float dd0[2][4];
#pragma unroll
        for (int nt = 0; nt < 2; ++nt) {
            float ld = 3.0e38f; int lj = 0;
#pragma unroll
            for (int j = 0; j < 4; ++j) {
                dd0[nt][j] = -2.f * acc[nt][j];
                if (dd0[nt][j] < ld) { ld = dd0[nt][j]; lj = j; }
            }
            unsigned pk = pack_dc(ld, cbase + lj);
            unsigned po = (unsigned)__shfl_xor((int)pk, 16, 64);
            pk = po < pk ? po : pk;
            po = (unsigned)__shfl_xor((int)pk, 32, 64);
            pk = po < pk ? po : pk;
            if (quad == 0) atomicMin(&runmin[nt * 16 + col], pk);
        }
        __syncthreads();                       // runmin holds row min over chunk 0
#pragma unroll
        for (int nt = 0; nt < 2; ++nt) {
            rm[nt]  = runmin[nt * 16 + col];
            thr[nt] = funkey(rm[nt] & 0xFFFFF800u) + TAU;
            const int r = nt * 16 + col;
#pragma unroll
            for (int j = 0; j < 4; ++j) {
                if (dd0[nt][j] < thr[nt]) {
                    unsigned s_ = atomicAdd(&cnt[r], 1u);
                    if (s_ < (unsigned)CAP)
                        cand[r * CAP + s_] = pack_dc(dd0[nt][j], cbase + j);
                }
            }
        }
    }

    // ---- chunks 1..31; thr re-sync at ch = 9, 17, 25 ----
    for (int ch = 1; ch < NCHUNK; ++ch) {
        if ((ch & 7) == 1 && ch != 1) {
#pragma unroll
            for (int nt = 0; nt < 2; ++nt) {
                unsigned pk = rm[nt];
                unsigned po = (unsigned)__shfl_xor((int)pk, 16, 64);
                pk = po < pk ? po : pk;
                po = (unsigned)__shfl_xor((int)pk, 32, 64);
                pk = po < pk ? po : pk;
                if (quad == 0) atomicMin(&runmin[nt * 16 + col], pk);
            }
            __syncthreads();
#pragma unroll
            for (int nt = 0; nt < 2; ++nt) {
                unsigned rv = runmin[nt * 16 + col];
                if (rv < rm[nt]) rm[nt] = rv;
                thr[nt] = funkey(rm[nt] & 0xFFFFF800u) + TAU;
            }
        }
        const int cb = ch * CHUNK;
        const int cbase = cb + wv * 16 + quad * 4;
        const float4 w2v = *reinterpret_cast<const float4*>(&w2l[cbase]);
        f32x4 acc[2];
#pragma unroll
        for (int nt = 0; nt < 2; ++nt)
            acc[nt] = (f32x4){w2v.x, w2v.y, w2v.z, w2v.w};
#pragma unroll
        for (int kk = 0; kk < 8; ++kk)
#pragma unroll
            for (int nt = 0; nt < 2; ++nt)
                acc[nt] = __builtin_amdgcn_mfma_f32_16x16x32_bf16(aw[kk], bx[nt][kk],
                                                                  acc[nt], 0, 0, 0);
        // prefetch next chunk into aw (single buffer; WAR clears at MFMA issue)
        {
            const unsigned short* wnp =
                wl + (size_t)(((ch + 1) & (NCHUNK - 1)) * 4) * 4096;
#pragma unroll
            for (int kk = 0; kk < 8; ++kk)
                aw[kk] = *reinterpret_cast<const short8*>(wnp + kk * 512);
        }
        // tail: min/collect (covers the prefetch L2 latency)
#pragma unroll
        for (int nt = 0; nt < 2; ++nt) {
            const float d0 = -2.f * acc[nt][0];
            const float d1 = -2.f * acc[nt][1];
            const float d2 = -2.f * acc[nt][2];
            const float d3 = -2.f * acc[nt][3];
            float ld = d0; int lj = 0;
            if (d1 < ld) { ld = d1; lj = 1; }
            if (d2 < ld) { ld = d2; lj = 2; }
            if (d3 < ld) { ld = d3; lj = 3; }
            const unsigned pk = pack_dc(ld, cbase + lj);
            if (pk < rm[nt]) { rm[nt] = pk; thr[nt] = funkey(pk & 0xFFFFF800u) + TAU; }
            const int r = nt * 16 + col;
            if (d0 < thr[nt]) { unsigned s_ = atomicAdd(&cnt[r], 1u);
                if (s_ < (unsigned)CAP) cand[r * CAP + s_] = pack_dc(d0, cbase + 0); }
            if (d1 < thr[nt]) { unsigned s_ = atomicAdd(&cnt[r], 1u);
                if (s_ < (unsigned)CAP) cand[r * CAP + s_] = pack_dc(d1, cbase + 1); }
            if (d2 < thr[nt]) { unsigned s_ = atomicAdd(&cnt[r], 1u);
                if (s_ < (unsigned)CAP) cand[r * CAP + s_] = pack_dc(d2, cbase + 2); }
            if (d3 < thr[nt]) { unsigned s_ = atomicAdd(&cnt[r], 1u);
                if (s_ < (unsigned)CAP) cand[r * CAP + s_] = pack_dc(d3, cbase + 3); }
        }
    }

    // ---- deferred final reduction: cross-quad min once, one atomicMin ----
#pragma unroll
    for (int nt = 0; nt < 2; ++nt) {
        unsigned pk = rm[nt];
        unsigned po = (unsigned)__shfl_xor((int)pk, 16, 64);
        pk = po < pk ? po : pk;
        po = (unsigned)__shfl_xor((int)pk, 32, 64);
        pk = po < pk ? po : pk;
        if (quad == 0) atomicMin(&runmin[nt * 16 + col], pk);
    }
    __syncthreads();

    // ---- select: unambiguous rows decided by bf16; near-ties -> refine ----
    if (tid < ROWS) {
        const unsigned key = runmin[tid];
        const int   c1 = (int)(key & 0x7FFu);
        const float d1 = funkey(key & 0xFFFFF800u);
        const unsigned thv = ((fkey(d1 + SLACK)) & 0xFFFFF800u) | 0x7FFu;
        const int n = (int)min(cnt[tid], (unsigned)CAP);
        int m = 0; bool have_c1 = false;
        for (int t = 0; t < n; ++t) {
            unsigned e = cand[tid * CAP + t];
            if (e <= thv) {
                int code = (int)(e & 0x7FFu);
                if (code == c1) have_c1 = true;
                cand[tid * CAP + m++] = (unsigned)code;
            }
        }
        if (!have_c1 && m < CAP) cand[tid * CAP + m++] = (unsigned)c1;
        bestc[tid] = c1; dbest[tid] = d1;
        scnt[tid] = (m >= 2) ? m : 0;
    }
    __syncthreads();

    // ---- exact fp32 refinement (round-2 numerics), ~6% of rows ----
    // (w2l holds -0.5*||w||^2, so d = -2*(w2l[code] + x.w))
    for (int r = wv; r < ROWS; r += 4) {
        const int m = scnt[r];
        if (m == 0) continue;
        const size_t xb = base + r;
        float xr0 = x[xb + (size_t)(4 * lane + 0) * HW];
        float xr1 = x[xb + (size_t)(4 * lane + 1) * HW];
        float xr2 = x[xb + (size_t)(4 * lane + 2) * HW];
        float xr3 = x[xb + (size_t)(4 * lane + 3) * HW];
        float bd = 1e38f; int bc = 0;
        for (int t = 0; t < m; ++t) {
            const int code = (int)cand[r * CAP + t];
            float4 wv4 = *reinterpret_cast<const float4*>(wg + (size_t)code * DIM + lane * 4);
            float sum = xr0 * wv4.x + xr1 * wv4.y + xr2 * wv4.z + xr3 * wv4.w;
#pragma unroll
            for (int o = 1; o < 64; o <<= 1) sum += __shfl_xor(sum, o, 64);
            float d = -2.0f * (w2l[code] + sum);
            if (t == 0 || d < bd || (d == bd && code < bc)) { bd = d; bc = code; }
        }
        if (lane == 0) { bestc[r] = bc; dbest[r] = bd; }
    }
    __syncthreads();

    // ---- loss via identity: sum_r (d_best + ||x||^2) = sum (q-x)^2 ----
    if (tid == 0) {
        float ls = 0.f;
        for (int r = 0; r < ROWS; ++r) ls += dbest[r] + xn2[r];
        atomicAdd(loss_slot, ls * LOSS_SCALE);
    }

    // ---- epilogue: 2 passes x 16 rows; stage codewords fp32 -> float4 out ----
    float* wst = (float*)ubuf;                    // [16][260]
    const int rl = tid >> 4;
    const int tt = tid & 15;
    const int ec = tid >> 2;                      // 0..63 (channel group)
    const int ei = (tid & 3) * 4;                 // 0,4,8,12 (spatial i0)
    for (int h = 0; h < 2; ++h) {
        __syncthreads();
        const float* wrow = wg + (size_t)bestc[h * 16 + rl] * DIM;
#pragma unroll
        for (int it = 0; it < 4; ++it) {
            const int c4 = it * 16 + tt;
            *reinterpret_cast<float4*>(wst + rl * 260 + c4 * 4) =
                *reinterpret_cast<const float4*>(wrow + c4 * 4);
        }
        __syncthreads();
#pragma unroll
        for (int it = 0; it < 4; ++it) {
            const int c = it * 64 + ec;
            float4 o;
            o.x = wst[(ei + 0) * 260 + c];
            o.y = wst[(ei + 1) * 260 + c];
            o.z = wst[(ei + 2) * 260 + c];
            o.w = wst[(ei + 3) * 260 + c];
            *reinterpret_cast<float4*>(out + base + (size_t)c * HW + h * 16 + ei) = o;
        }
    }
}

extern "C" void kernel_launch(void* const* d_in, const int* in_sizes, int n_in,
                              void* d_out, int out_size, void* d_ws, size_t ws_size,
                              hipStream_t stream) {
    const float* x = (const float*)d_in[0];
    const float* w = (const float*)d_in[1];
    float* out       = (float*)d_out;
    float* loss_slot = out + NTOT;
    unsigned short* wfrag = (unsigned short*)d_ws;   // 1 MB fragment-ordered bf16 w
    float* w2 = (float*)((char*)d_ws + (size_t)NE * DIM * sizeof(unsigned short));

    prep_kernel<<<NE / 4, 256, 0, stream>>>(w, wfrag, w2, loss_slot);
    vq_kernel<<<65536 / ROWS, 256, 0, stream>>>(x, w, wfrag, w2, out, loss_slot);
}

// Round 13
// 213.101 us; speedup vs baseline: 2.3309x; 1.0090x over previous
//
#include <hip/hip_runtime.h>

// VQ quantizer forward: direct-from-L2 bf16-MFMA distance GEMM.
// ROWS=32 / nt=2 (2 MFMA chains for ILP) / single-buffered A-frags, register
// cap forced to 4 waves/SIMD via __launch_bounds__(256,4). Fragment-ordered w
// staging, lane-local running-min thresholds re-synced via LDS every 8 chunks,
// exact fp32 candidate refinement. s_setprio(1) wraps the MFMA cluster (T5:
// barrier-free loop => waves at different phases => scheduler can favor the
// MFMA-entering wave; zero register cost). x (16,256,64,64) fp32,
// w (2048,256) fp32. d_out = 16,777,216 floats + 1 float (latent loss).
//
// NOTE (R8-R10 lessons): this kernel sits at EXACTLY 128 combined VGPR+AGPR
// (bx 64 AGPR + aw 32 + acc 8 + temps). Any added main-loop liveness (held
// w2v across MFMAs, packed-key temps across a branch, tighter bounds) spills
// to scratch and regresses 10-220%. Do not touch the main loop's liveness.

typedef __attribute__((ext_vector_type(8))) short short8;  // 8 bf16 (4 VGPR)
typedef __attribute__((ext_vector_type(4))) float f32x4;   // MFMA C/D

constexpr int NE   = 2048;
constexpr int DIM  = 256;
constexpr int HW   = 4096;
constexpr int NTOT = 16777216;
constexpr int ROWS   = 32;      // spatial rows per block
constexpr int CHUNK  = 64;      // codes per main-loop iteration
constexpr int NCHUNK = NE / CHUNK;
constexpr int CAP    = 64;      // candidate list capacity per row
constexpr float TAU   = 0.75f;  // collect window (bf16-MFMA err ~17 sigma)
constexpr float SLACK = 1.0f;   // ambiguity window triggering fp32 refine
constexpr float LOSS_SCALE = 0.25f / 16777216.0f;

__device__ __forceinline__ unsigned short f2bf(float f) {  // RNE fp32->bf16
    unsigned u = __builtin_bit_cast(unsigned, f);
    u += 0x7fffu + ((u >> 16) & 1u);
    return (unsigned short)(u >> 16);
}
// monotone float<->uint keys (works for negative distances too)
__device__ __forceinline__ unsigned fkey(float f) {
    unsigned u = __builtin_bit_cast(unsigned, f);
    return u ^ ((unsigned)((int)u >> 31) | 0x80000000u);
}
__device__ __forceinline__ float funkey(unsigned k) {
    unsigned u = (k & 0x80000000u) ? (k & 0x7fffffffu) : ~k;
    return __builtin_bit_cast(float, u);
}
// packed candidate/runmin entry: truncated fkey (21 bits kept) | code (11 bits)
__device__ __forceinline__ unsigned pack_dc(float d, int code) {
    return (fkey(d) & 0xFFFFF800u) | (unsigned)code;
}

// Kernel 1: -0.5*||w||^2 (pre-scaled for acc-init) + FRAGMENT-ORDERED bf16
// copy of w; also zero loss slot.
// wfrag layout: group g=code>>4 (16 codes); within group: [kk][quad][col][8e].
// vq_kernel loads aw[kk] at wfrag + g*4096 + kk*512 + lane*8 -- fully
// coalesced 1KB per instruction.
__global__ __launch_bounds__(256) void prep_kernel(const float* __restrict__ w,
                                                   unsigned short* __restrict__ wfrag,
                                                   float* __restrict__ w2,
                                                   float* __restrict__ loss_slot) {
    const int lane = threadIdx.x & 63;
    const int wv   = threadIdx.x >> 6;
    const int code = blockIdx.x * 4 + wv;   // one wave per code row
    float4 v = *reinterpret_cast<const float4*>(w + (size_t)code * DIM + lane * 4);
    float s = v.x * v.x + v.y * v.y + v.z * v.z + v.w * v.w;
#pragma unroll
    for (int off = 32; off > 0; off >>= 1) s += __shfl_down(s, off, 64);
    if (lane == 0) w2[code] = -0.5f * s;    // pre-scaled: acc-init consumes directly
    ushort4 u4;
    u4.x = f2bf(v.x); u4.y = f2bf(v.y); u4.z = f2bf(v.z); u4.w = f2bf(v.w);
    const size_t off = (size_t)(code >> 4) * 4096 + (lane >> 3) * 512 +
                       ((lane >> 1) & 3) * 128 + (code & 15) * 8 + (lane & 1) * 4;
    *reinterpret_cast<ushort4*>(wfrag + off) = u4;
    if (blockIdx.x == 0 && threadIdx.x == 0) *loss_slot = 0.0f;
}

__global__ __launch_bounds__(256, 4) void vq_kernel(const float* __restrict__ x,
                                                    const float* __restrict__ wg,
                                                    const unsigned short* __restrict__ wfrag,
                                                    const float* __restrict__ w2g,
                                                    float* __restrict__ out,
                                                    float* __restrict__ loss_slot) {
    // ubuf reused: phase1 bf16 x-transpose [32][264] / epilogue staging [16][260] f32
    __shared__ alignas(16) unsigned char ubuf[16896];
    __shared__ unsigned runmin[ROWS];     // packed (trunc fkey | code), atomicMin
    __shared__ unsigned cand[ROWS * CAP]; // packed entries (8 KB)
    __shared__ unsigned cnt[ROWS];
    __shared__ float    dbest[ROWS];
    __shared__ int      bestc[ROWS];
    __shared__ int      scnt[ROWS];
    __shared__ float    xn2[ROWS];        // per-row ||x||^2 (fp32 exact)
    __shared__ float    w2l[NE];          // -0.5*||w||^2 staged once (8 KB)

    const int tid = threadIdx.x;
    const int blk = blockIdx.x;
    const int b   = blk >> 7;             // 128 blocks per image (4096/32)
    const int hw0 = (blk & 127) << 5;
    const size_t base = (size_t)b * (DIM * HW) + hw0;

    const int wv   = tid >> 6;
    const int lane = tid & 63;
    const int col  = lane & 15;
    const int quad = lane >> 4;

    if (tid < ROWS) { runmin[tid] = 0xFFFFFFFFu; cnt[tid] = 0u; xn2[tid] = 0.f; }

    // stage w2 -> LDS (visibility covered by phase-1 barriers)
    {
        float4* dst = reinterpret_cast<float4*>(w2l);
        const float4* src = reinterpret_cast<const float4*>(w2g);
        dst[tid]       = src[tid];
        dst[tid + 256] = src[tid + 256];
    }

    // ---- phase 1: stage x as bf16 (one pass, 32 rows), B-frags = ds_read ----
    unsigned short* xst = (unsigned short*)ubuf;  // [32][264] bf16
    short8 bx[2][8];                      // B[k=kk*32+quad*8+j][n=nt*16+col]
    const int irow = tid & 31;
    const int cgrp = tid >> 5;
    {
        float myxn2 = 0.f;
        for (int it = 0; it < 32; ++it) {
            int c = it * 8 + cgrp;
            float v = x[base + (size_t)c * HW + irow];
            xst[irow * 264 + c] = f2bf(v);
            myxn2 = fmaf(v, v, myxn2);
        }
        atomicAdd(&xn2[irow], myxn2);
        __syncthreads();
#pragma unroll
        for (int t = 0; t < 2; ++t) {
            const unsigned short* xr = xst + (t * 16 + col) * 264 + quad * 8;
#pragma unroll
            for (int kk = 0; kk < 8; ++kk)
                bx[t][kk] = *reinterpret_cast<const short8*>(xr + kk * 32);
        }
    }

    // ---- main loop: barrier-free chunk bodies, A-frags direct from global
    // (L2-hot wfrag, coalesced 1KB loads), SINGLE-buffered: prefetch of ch+1
    // issues right after the last MFMA reads aw; the tail VALU covers the L2
    // latency. Lane-local running min + threshold, re-synced via LDS runmin
    // every 8 chunks. ----
    unsigned rm[2]  = {0xFFFFFFFFu, 0xFFFFFFFFu};
    float    thr[2] = {3.0e38f, 3.0e38f};
    short8 aw[8];
    // this wave's fragment base for chunk ch: wfrag + (ch*4+wv)*4096 + lane*8
    const unsigned short* wl = wfrag + (size_t)wv * 4096 + (size_t)lane * 8;
#pragma unroll
    for (int kk = 0; kk < 8; ++kk)        // chunk 0 A-frags
        aw[kk] = *reinterpret_cast<const short8*>(wl + kk * 512);

    // ---- chunk 0 (special): compute, row-sync threshold, then collect ----
    {
        const int cbase = wv * 16 + quad * 4;
        const float4 w2v = *reinterpret_cast<const float4*>(&w2l[cbase]);
        f32x4 acc[2];
#pragma unroll
        for (int nt = 0; nt < 2; ++nt)
            acc[nt] = (f32x4){w2v.x, w2v.y, w2v.z, w2v.w};
        __builtin_amdgcn_s_setprio(1);
#pragma unroll
        for (int kk = 0; kk < 8; ++kk)
#pragma unroll
            for (int nt = 0; nt < 2; ++nt)
                acc[nt] = __builtin_amdgcn_mfma_f32_16x16x32_bf16(aw[kk], bx[nt][kk],
                                                                  acc[nt], 0, 0, 0);
        __builtin_amdgcn_s_setprio(0);
        // prefetch chunk 1 into aw (after last use above)
        {
            const unsigned short* wnp = wl + 4 * 4096;
#pragma unroll
            for (int kk = 0; kk < 8; ++kk)
                aw[kk] = *reinterpret_cast<const short8*>(wnp + kk * 512);
        }
        float dd0[2][4];
#pragma unroll
        for (int nt = 0; nt < 2; ++nt) {
            float ld = 3.0e38f; int lj = 0;
#pragma unroll
            for (int j = 0; j < 4; ++j) {
                dd0[nt][j] = -2.f * acc[nt][j];
                if (dd0[nt][j] < ld) { ld = dd0[nt][j]; lj = j; }
            }
            unsigned pk = pack_dc(ld, cbase + lj);
            unsigned po = (unsigned)__shfl_xor((int)pk, 16, 64);
            pk = po < pk ? po : pk;
            po = (unsigned)__shfl_xor((int)pk, 32, 64);
            pk = po < pk ? po : pk;
            if (quad == 0) atomicMin(&runmin[nt * 16 + col], pk);
        }
        __syncthreads();                       // runmin holds row min over chunk 0
#pragma unroll
        for (int nt = 0; nt < 2; ++nt) {
            rm[nt]  = runmin[nt * 16 + col];
            thr[nt] = funkey(rm[nt] & 0xFFFFF800u) + TAU;
            const int r = nt * 16 + col;
#pragma unroll
            for (int j = 0; j < 4; ++j) {
                if (dd0[nt][j] < thr[nt]) {
                    unsigned s_ = atomicAdd(&cnt[r], 1u);
                    if (s_ < (unsigned)CAP)
                        cand[r * CAP + s_] = pack_dc(dd0[nt][j], cbase + j);
                }
            }
        }
    }

    // ---- chunks 1..31; thr re-sync at ch = 9, 17, 25 ----
    for (int ch = 1; ch < NCHUNK; ++ch) {
        if ((ch & 7) == 1 && ch != 1) {
#pragma unroll
            for (int nt = 0; nt < 2; ++nt) {
                unsigned pk = rm[nt];
                unsigned po = (unsigned)__shfl_xor((int)pk, 16, 64);
                pk = po < pk ? po : pk;
                po = (unsigned)__shfl_xor((int)pk, 32, 64);
                pk = po < pk ? po : pk;
                if (quad == 0) atomicMin(&runmin[nt * 16 + col], pk);
            }
            __syncthreads();
#pragma unroll
            for (int nt = 0; nt < 2; ++nt) {
                unsigned rv = runmin[nt * 16 + col];
                if (rv < rm[nt]) rm[nt] = rv;
                thr[nt] = funkey(rm[nt] & 0xFFFFF800u) + TAU;
            }
        }
        const int cb = ch * CHUNK;
        const int cbase = cb + wv * 16 + quad * 4;
        const float4 w2v = *reinterpret_cast<const float4*>(&w2l[cbase]);
        f32x4 acc[2];
#pragma unroll
        for (int nt = 0; nt < 2; ++nt)
            acc[nt] = (f32x4){w2v.x, w2v.y, w2v.z, w2v.w};
        __builtin_amdgcn_s_setprio(1);
#pragma unroll
        for (int kk = 0; kk < 8; ++kk)
#pragma unroll
            for (int nt = 0; nt < 2; ++nt)
                acc[nt] = __builtin_amdgcn_mfma_f32_16x16x32_bf16(aw[kk], bx[nt][kk],
                                                                  acc[nt], 0, 0, 0);
        __builtin_amdgcn_s_setprio(0);
        // prefetch next chunk into aw (single buffer; WAR clears at MFMA issue)
        {
            const unsigned short* wnp =
                wl + (size_t)(((ch + 1) & (NCHUNK - 1)) * 4) * 4096;
#pragma unroll
            for (int kk = 0; kk < 8; ++kk)
                aw[kk] = *reinterpret_cast<const short8*>(wnp + kk * 512);
        }
        // tail: min/collect (covers the prefetch L2 latency)
#pragma unroll
        for (int nt = 0; nt < 2; ++nt) {
            const float d0 = -2.f * acc[nt][0];
            const float d1 = -2.f * acc[nt][1];
            const float d2 = -2.f * acc[nt][2];
            const float d3 = -2.f * acc[nt][3];
            float ld = d0; int lj = 0;
            if (d1 < ld) { ld = d1; lj = 1; }
            if (d2 < ld) { ld = d2; lj = 2; }
            if (d3 < ld) { ld = d3; lj = 3; }
            const unsigned pk = pack_dc(ld, cbase + lj);
            if (pk < rm[nt]) { rm[nt] = pk; thr[nt] = funkey(pk & 0xFFFFF800u) + TAU; }
            const int r = nt * 16 + col;
            if (d0 < thr[nt]) { unsigned s_ = atomicAdd(&cnt[r], 1u);
                if (s_ < (unsigned)CAP) cand[r * CAP + s_] = pack_dc(d0, cbase + 0); }
            if (d1 < thr[nt]) { unsigned s_ = atomicAdd(&cnt[r], 1u);
                if (s_ < (unsigned)CAP) cand[r * CAP + s_] = pack_dc(d1, cbase + 1); }
            if (d2 < thr[nt]) { unsigned s_ = atomicAdd(&cnt[r], 1u);
                if (s_ < (unsigned)CAP) cand[r * CAP + s_] = pack_dc(d2, cbase + 2); }
            if (d3 < thr[nt]) { unsigned s_ = atomicAdd(&cnt[r], 1u);
                if (s_ < (unsigned)CAP) cand[r * CAP + s_] = pack_dc(d3, cbase + 3); }
        }
    }

    // ---- deferred final reduction: cross-quad min once, one atomicMin ----
#pragma unroll
    for (int nt = 0; nt < 2; ++nt) {
        unsigned pk = rm[nt];
        unsigned po = (unsigned)__shfl_xor((int)pk, 16, 64);
        pk = po < pk ? po : pk;
        po = (unsigned)__shfl_xor((int)pk, 32, 64);
        pk = po < pk ? po : pk;
        if (quad == 0) atomicMin(&runmin[nt * 16 + col], pk);
    }
    __syncthreads();

    // ---- select: unambiguous rows decided by bf16; near-ties -> refine ----
    if (tid < ROWS) {
        const unsigned key = runmin[tid];
        const int   c1 = (int)(key & 0x7FFu);
        const float d1 = funkey(key & 0xFFFFF800u);
        const unsigned thv = ((fkey(d1 + SLACK)) & 0xFFFFF800u) | 0x7FFu;
        const int n = (int)min(cnt[tid], (unsigned)CAP);
        int m = 0; bool have_c1 = false;
        for (int t = 0; t < n; ++t) {
            unsigned e = cand[tid * CAP + t];
            if (e <= thv) {
                int code = (int)(e & 0x7FFu);
                if (code == c1) have_c1 = true;
                cand[tid * CAP + m++] = (unsigned)code;
            }
        }
        if (!have_c1 && m < CAP) cand[tid * CAP + m++] = (unsigned)c1;
        bestc[tid] = c1; dbest[tid] = d1;
        scnt[tid] = (m >= 2) ? m : 0;
    }
    __syncthreads();

    // ---- exact fp32 refinement (round-2 numerics), ~6% of rows ----
    // (w2l holds -0.5*||w||^2, so d = -2*(w2l[code] + x.w))
    for (int r = wv; r < ROWS; r += 4) {
        const int m = scnt[r];
        if (m == 0) continue;
        const size_t xb = base + r;
        float xr0 = x[xb + (size_t)(4 * lane + 0) * HW];
        float xr1 = x[xb + (size_t)(4 * lane + 1) * HW];
        float xr2 = x[xb + (size_t)(4 * lane + 2) * HW];
        float xr3 = x[xb + (size_t)(4 * lane + 3) * HW];
        float bd = 1e38f; int bc = 0;
        for (int t = 0; t < m; ++t) {
            const int code = (int)cand[r * CAP + t];
            float4 wv4 = *reinterpret_cast<const float4*>(wg + (size_t)code * DIM + lane * 4);
            float sum = xr0 * wv4.x + xr1 * wv4.y + xr2 * wv4.z + xr3 * wv4.w;
#pragma unroll
            for (int o = 1; o < 64; o <<= 1) sum += __shfl_xor(sum, o, 64);
            float d = -2.0f * (w2l[code] + sum);
            if (t == 0 || d < bd || (d == bd && code < bc)) { bd = d; bc = code; }
        }
        if (lane == 0) { bestc[r] = bc; dbest[r] = bd; }
    }
    __syncthreads();

    // ---- loss via identity: sum_r (d_best + ||x||^2) = sum (q-x)^2 ----
    if (tid == 0) {
        float ls = 0.f;
        for (int r = 0; r < ROWS; ++r) ls += dbest[r] + xn2[r];
        atomicAdd(loss_slot, ls * LOSS_SCALE);
    }

    // ---- epilogue: 2 passes x 16 rows; stage codewords fp32 -> float4 out ----
    float* wst = (float*)ubuf;                    // [16][260]
    const int rl = tid >> 4;
    const int tt = tid & 15;
    const int ec = tid >> 2;                      // 0..63 (channel group)
    const int ei = (tid & 3) * 4;                 // 0,4,8,12 (spatial i0)
    for (int h = 0; h < 2; ++h) {
        __syncthreads();
        const float* wrow = wg + (size_t)bestc[h * 16 + rl] * DIM;
#pragma unroll
        for (int it = 0; it < 4; ++it) {
            const int c4 = it * 16 + tt;
            *reinterpret_cast<float4*>(wst + rl * 260 + c4 * 4) =
                *reinterpret_cast<const float4*>(wrow + c4 * 4);
        }
        __syncthreads();
#pragma unroll
        for (int it = 0; it < 4; ++it) {
            const int c = it * 64 + ec;
            float4 o;
            o.x = wst[(ei + 0) * 260 + c];
            o.y = wst[(ei + 1) * 260 + c];
            o.z = wst[(ei + 2) * 260 + c];
            o.w = wst[(ei + 3) * 260 + c];
            *reinterpret_cast<float4*>(out + base + (size_t)c * HW + h * 16 + ei) = o;
        }
    }
}

extern "C" void kernel_launch(void* const* d_in, const int* in_sizes, int n_in,
                              void* d_out, int out_size, void* d_ws, size_t ws_size,
                              hipStream_t stream) {
    const float* x = (const float*)d_in[0];
    const float* w = (const float*)d_in[1];
    float* out       = (float*)d_out;
    float* loss_slot = out + NTOT;
    unsigned short* wfrag = (unsigned short*)d_ws;   // 1 MB fragment-ordered bf16 w
    float* w2 = (float*)((char*)d_ws + (size_t)NE * DIM * sizeof(unsigned short));

    prep_kernel<<<NE / 4, 256, 0, stream>>>(w, wfrag, w2, loss_slot);
    vq_kernel<<<65536 / ROWS, 256, 0, stream>>>(x, w, wfrag, w2, out, loss_slot);
}